// Round 21
// baseline (142.727 us; speedup 1.0000x reference)
//
#include <hip/hip_runtime.h>
#include <hip/hip_bf16.h>

#define D_MODEL 1024
#define NHEADS 16
#define HD 64
#define BATCH 2
#define SEQ 2048
#define BS (BATCH*SEQ)   // 4096

typedef __bf16 bf16;
typedef bf16 bf16x4 __attribute__((ext_vector_type(4)));
typedef bf16 bf16x8 __attribute__((ext_vector_type(8)));
typedef float f32x4 __attribute__((ext_vector_type(4)));

#define AS1 __attribute__((address_space(1)))
#define AS3 __attribute__((address_space(3)))

__device__ __forceinline__ void gload_lds16(const void* g, void* l) {
  __builtin_amdgcn_global_load_lds((AS1 const unsigned int*)g, (AS3 unsigned int*)l, 16, 0, 0);
}

// 2^x: prefer the compiler builtin (raw v_exp_f32); asm fallback.
__device__ __forceinline__ float exp2_fast(float x) {
#if __has_builtin(__builtin_amdgcn_exp2f)
  return __builtin_amdgcn_exp2f(x);
#else
  float r;
  asm("v_exp_f32 %0, %1\n\ts_nop 1" : "=v"(r) : "v"(x));
  return r;
#endif
}

// ---------------- prep: 3 weight transposes only -----------------------------
// (x/y conversion eliminated: qkv stages A directly from f32 with in-register
// cvt; mask scan lives in the qkv dispatch.)
__global__ __launch_bounds__(256)
void prep_kernel(const float* __restrict__ Wkv, const float* __restrict__ Wq,
                 const float* __restrict__ Wo,
                 bf16* __restrict__ Wkvt, bf16* __restrict__ Wqt,
                 bf16* __restrict__ Wot) {
  __shared__ bf16 tile[64][72];
  const int blk = blockIdx.x;
  const int t = threadIdx.x;

  const float* tin; bf16* tout; int C, tt;
  if (blk < 512)       { tin = Wkv; tout = Wkvt; C = 2048; tt = blk; }
  else if (blk < 768)  { tin = Wq;  tout = Wqt;  C = 1024; tt = blk - 512; }
  else                 { tin = Wo;  tout = Wot;  C = 1024; tt = blk - 768; }
  const int R = 1024;
  const int r0 = (tt & 15) * 64;
  const int c0 = (tt >> 4) * 64;
  {
    int r = t >> 2, cc = (t & 3) * 16;
    const float* src = tin + (size_t)(r0 + r) * C + c0 + cc;
    #pragma unroll
    for (int j = 0; j < 16; j += 4) {
      float4 v = *(const float4*)(src + j);
      tile[r][cc + j + 0] = (bf16)v.x;
      tile[r][cc + j + 1] = (bf16)v.y;
      tile[r][cc + j + 2] = (bf16)v.z;
      tile[r][cc + j + 3] = (bf16)v.w;
    }
  }
  __syncthreads();
  {
    int c = t >> 2, rr = (t & 3) * 16;
    bf16* dst = tout + (size_t)(c0 + c) * R + r0 + rr;
    bf16x8 o0, o1;
    #pragma unroll
    for (int j = 0; j < 8; j++) { o0[j] = tile[rr + j][c]; o1[j] = tile[rr + 8 + j][c]; }
    *(bf16x8*)dst = o0;
    *(bf16x8*)(dst + 8) = o1;
  }
}

// ---------------- fused QKV projection GEMM + mask scan ----------------------
// grid (32, 32):
//   by<16        -> KV tile (A = x, f32, reg-staged cvt): wc==0 waves write
//                   K half COMPACTED to Kc[4096][1024]; wc==1 waves write V
//                   half TRANSPOSED to Vt.
//   by in [16,24)-> Q tile (A = y), output scaled by QSCL (exp2 domain).
//   by in [24,32)-> mask zero-scan blocks (hidden under GEMM compute).
// A staging: 32B f32 load at the pre-swizzled offset (x2 of the bf16 byte
// offset), in-register cvt, ds_write_b128 to the SAME linear LDS slot the
// gload_lds path used -> layout identical. B stays async gload_lds, issued
// FIRST so its in-flight latency covers the synchronous A loads.
__global__ __launch_bounds__(256)
void qkv_gemm(const float* __restrict__ xf, const float* __restrict__ yf,
              const bf16* __restrict__ Wkvt, const bf16* __restrict__ Wqt,
              const float* __restrict__ bkv, const float* __restrict__ bq,
              const float* __restrict__ mask, int* __restrict__ flag,
              bf16* __restrict__ Kc, bf16* __restrict__ Qbuf,
              bf16* __restrict__ Vt, float QSCL) {
  const int by = blockIdx.y;
  const int t = threadIdx.x;

  if (by >= 24) {
    // mask zero-scan: 256 blocks x 256 threads, grid-stride over float4s
    const int n4 = BATCH * SEQ * SEQ / 4;
    int i = ((by - 24) * 32 + blockIdx.x) * 256 + t;
    const int stride = 256 * 256;
    int any = 0;
    for (; i < n4; i += stride) {
      float4 v = *(const float4*)(mask + (size_t)i * 4);
      if (v.x != 0.f || v.y != 0.f || v.z != 0.f || v.w != 0.f) any = 1;
    }
    if (__ballot(any) && (t & 63) == 0) atomicOr(flag, 1);
    return;
  }

  __shared__ char lds[32768];
  char* Alds = lds;
  char* Blds = lds + 16384;
  const int K = 1024;
  const int lane = t & 63;
  const int wid = t >> 6;
  const int m0 = blockIdx.x * 128;
  const bool isQ = by >= 16;
  const int n0 = (isQ ? by - 16 : by) * 128;
  const char* Af = (const char*)(isQ ? yf : xf);   // f32 A source
  const bf16* Bt = isQ ? Wqt : Wkvt;
  const int wr = wid >> 1, wc = wid & 1;

  f32x4 acc[4][4] = {};

  int rowL[4], colL[4];
  #pragma unroll
  for (int i = 0; i < 4; i++) {
    int L = t * 16 + i * 4096;
    int r = L >> 7;
    rowL[i] = r;
    colL[i] = (L & 127) ^ ((r & 7) << 4);
  }
  const char* Bb = (const char*)Bt;
  const size_t rs = (size_t)K * 2;      // bf16 row stride (B)
  const size_t rsA = (size_t)K * 4;     // f32 row stride (A)

  for (int k0 = 0; k0 < K; k0 += 64) {
    // B first: async global->LDS, stays in flight while A converts
    #pragma unroll
    for (int i = 0; i < 4; i++)
      gload_lds16(Bb + (size_t)(n0 + rowL[i]) * rs + (size_t)k0 * 2 + colL[i],
                  Blds + i * 4096 + t * 16);
    // A: f32 load at 2x byte offset, cvt, write to the same linear slot
    #pragma unroll
    for (int i = 0; i < 4; i++) {
      const float4* sp = (const float4*)(Af + (size_t)(m0 + rowL[i]) * rsA
                                            + (size_t)k0 * 4 + colL[i] * 2);
      float4 a4 = sp[0], b4 = sp[1];
      bf16x8 o;
      o[0]=(bf16)a4.x; o[1]=(bf16)a4.y; o[2]=(bf16)a4.z; o[3]=(bf16)a4.w;
      o[4]=(bf16)b4.x; o[5]=(bf16)b4.y; o[6]=(bf16)b4.z; o[7]=(bf16)b4.w;
      *(bf16x8*)(Alds + i * 4096 + t * 16) = o;
    }
    __syncthreads();
    #pragma unroll
    for (int kb = 0; kb < 2; kb++) {
      bf16x8 af[4], bfr[4];
      #pragma unroll
      for (int m = 0; m < 4; m++) {
        int r = wr * 64 + m * 16 + (lane & 15);
        int cb = (kb * 64 + ((lane >> 4) << 4)) ^ ((r & 7) << 4);
        af[m] = *(const bf16x8*)(Alds + r * 128 + cb);
      }
      #pragma unroll
      for (int n = 0; n < 4; n++) {
        int r = wc * 64 + n * 16 + (lane & 15);
        int cb = (kb * 64 + ((lane >> 4) << 4)) ^ ((r & 7) << 4);
        bfr[n] = *(const bf16x8*)(Blds + r * 128 + cb);
      }
      #pragma unroll
      for (int m = 0; m < 4; m++)
        #pragma unroll
        for (int n = 0; n < 4; n++)
          acc[m][n] = __builtin_amdgcn_mfma_f32_16x16x32_bf16(af[m], bfr[n], acc[m][n], 0, 0, 0);
    }
    __syncthreads();
  }

  if (!isQ && wc == 1) {
    // V half -> Vt[B][H][HD][SEQ], transposed in epilogue
    const int h = n0 >> 7;
    const int bb = m0 >> 11;
    #pragma unroll
    for (int n = 0; n < 4; n++) {
      const int d = n * 16 + (lane & 15);
      const float bv = bkv[n0 + 64 + d];
      bf16* vrow = Vt + ((size_t)((bb * NHEADS + h) * HD + d)) * SEQ;
      #pragma unroll
      for (int m = 0; m < 4; m++) {
        const int rb = m0 + wr * 64 + m * 16 + ((lane >> 4) << 2);
        const int s = rb & (SEQ - 1);
        bf16x4 v;
        #pragma unroll
        for (int j = 0; j < 4; j++) v[j] = (bf16)(acc[m][n][j] + bv);
        *(bf16x4*)(vrow + s) = v;
      }
    }
  } else if (!isQ) {
    // K half -> Kc[4096][1024], col = h*64 + d  (h = n0>>7, d = n*16+lq)
    #pragma unroll
    for (int m = 0; m < 4; m++) {
      const int rb = m0 + wr * 64 + m * 16 + ((lane >> 4) << 2);
      #pragma unroll
      for (int n = 0; n < 4; n++) {
        const int cg = n0 + n * 16 + (lane & 15);            // bias index
        const int cc = (n0 >> 1) + n * 16 + (lane & 15);     // compact col
        const float bv = bkv[cg];
        #pragma unroll
        for (int j = 0; j < 4; j++)
          Kc[(size_t)(rb + j) * 1024 + cc] = (bf16)(acc[m][n][j] + bv);
      }
    }
  } else {
    #pragma unroll
    for (int m = 0; m < 4; m++) {
      const int rb = m0 + wr * 64 + m * 16 + ((lane >> 4) << 2);
      #pragma unroll
      for (int n = 0; n < 4; n++) {
        const int cg = n0 + wc * 64 + n * 16 + (lane & 15);
        const float bv = bq[cg];
        #pragma unroll
        for (int j = 0; j < 4; j++)
          Qbuf[(size_t)(rb + j) * 1024 + cg] = (bf16)((acc[m][n][j] + bv) * QSCL);
      }
    }
  }
}

// ---------------- O GEMM: out = vals @ Wot^T + bo, 64x128 tiles --------------
__global__ __launch_bounds__(256)
void gemm_o(const bf16* __restrict__ A, const bf16* __restrict__ Bt,
            const float* __restrict__ bias, float* __restrict__ C,
            int M, int N, int K) {
  __shared__ char lds[24576];
  char* Alds = lds;            // 64 rows x 128B
  char* Blds = lds + 8192;     // 128 rows x 128B
  const int t = threadIdx.x;
  const int lane = t & 63;
  const int wid = t >> 6;
  const int m0 = blockIdx.x * 64;
  const int n0 = blockIdx.y * 128;
  const int wr = wid >> 1, wc = wid & 1;

  f32x4 acc[2][4] = {};

  int rowL[4], colL[4];
  #pragma unroll
  for (int i = 0; i < 4; i++) {
    int L = t * 16 + i * 4096;
    int r = L >> 7;
    rowL[i] = r;
    colL[i] = (L & 127) ^ ((r & 7) << 4);
  }
  const char* Ab = (const char*)A;
  const char* Bb = (const char*)Bt;
  const size_t rs = (size_t)K * 2;

  for (int k0 = 0; k0 < K; k0 += 64) {
    #pragma unroll
    for (int i = 0; i < 2; i++)
      gload_lds16(Ab + (size_t)(m0 + rowL[i]) * rs + (size_t)k0 * 2 + colL[i],
                  Alds + i * 4096 + t * 16);
    #pragma unroll
    for (int i = 0; i < 4; i++)
      gload_lds16(Bb + (size_t)(n0 + rowL[i]) * rs + (size_t)k0 * 2 + colL[i],
                  Blds + i * 4096 + t * 16);
    __syncthreads();
    #pragma unroll
    for (int kb = 0; kb < 2; kb++) {
      bf16x8 af[2], bfr[4];
      #pragma unroll
      for (int m = 0; m < 2; m++) {
        int r = wr * 32 + m * 16 + (lane & 15);
        int cb = (kb * 64 + ((lane >> 4) << 4)) ^ ((r & 7) << 4);
        af[m] = *(const bf16x8*)(Alds + r * 128 + cb);
      }
      #pragma unroll
      for (int n = 0; n < 4; n++) {
        int r = wc * 64 + n * 16 + (lane & 15);
        int cb = (kb * 64 + ((lane >> 4) << 4)) ^ ((r & 7) << 4);
        bfr[n] = *(const bf16x8*)(Blds + r * 128 + cb);
      }
      #pragma unroll
      for (int m = 0; m < 2; m++)
        #pragma unroll
        for (int n = 0; n < 4; n++)
          acc[m][n] = __builtin_amdgcn_mfma_f32_16x16x32_bf16(af[m], bfr[n], acc[m][n], 0, 0, 0);
    }
    __syncthreads();
  }

  #pragma unroll
  for (int m = 0; m < 2; m++) {
    const int rb = m0 + wr * 32 + m * 16 + ((lane >> 4) << 2);
    #pragma unroll
    for (int n = 0; n < 4; n++) {
      const int cg = n0 + wc * 64 + n * 16 + (lane & 15);
      const float bv = bias[cg];
      #pragma unroll
      for (int j = 0; j < 4; j++)
        C[(size_t)(rb + j) * N + cg] = acc[m][n][j] + bv;
    }
  }
}

// ---------------- flash attention (r19 structure, verbatim) ------------------
// 4 waves x 32 q-rows = 128 q/block; grid = 512; 2 blocks/CU (measured
// optimum). Swapped QK^T; shared mrun across m (row-consistent); defer-max
// THR=8; per-lane lrun; builtin exp2; no fences.
__global__ __launch_bounds__(256)
void attn_kernel(const bf16* __restrict__ Qb, const bf16* __restrict__ Kc,
                 const bf16* __restrict__ Vt, const float* __restrict__ mask,
                 const int* __restrict__ flag, bf16* __restrict__ vals) {
  __shared__ char lds[49152];
  const int t = threadIdx.x;
  const int lane = t & 63;
  const int wid = t >> 6;
  const int g = lane >> 4;
  const int lq = lane & 15;
  char* Pw = lds + 32768 + wid * 4096;

  // XCD swizzle: 512 blocks, 8 XCDs, 64 consecutive wgs/XCD (4 heads).
  int wg = ((blockIdx.x & 7) << 6) | (blockIdx.x >> 3);
  const int qt = wg & 15;
  const int h = (wg >> 4) & 15;
  const int b = wg >> 8;
  const int q0 = qt * 128 + wid * 32;
  const bool use_mask = (*flag) != 0;

  bf16x8 qf[2][2];
  #pragma unroll
  for (int m = 0; m < 2; m++)
    #pragma unroll
    for (int kb = 0; kb < 2; kb++) {
      int r = q0 + m * 16 + lq;
      qf[m][kb] = *(const bf16x8*)(Qb + (size_t)(b * SEQ + r) * D_MODEL + h * HD + kb * 32 + g * 8);
    }

  f32x4 oacc[2][4] = {};
  float mrun = -1e30f;
  float lrun[2] = {0.f, 0.f};

  int kvOff[2][4];
  #pragma unroll
  for (int kb = 0; kb < 2; kb++)
    #pragma unroll
    for (int n = 0; n < 4; n++) {
      int r = n * 16 + lq;
      kvOff[kb][n] = r * 128 + ((kb * 64 + (g << 4)) ^ ((r & 7) << 4));
    }
  int pROff[2][2];
  #pragma unroll
  for (int m = 0; m < 2; m++)
    #pragma unroll
    for (int kb = 0; kb < 2; kb++) {
      int r = m * 16 + lq;
      pROff[m][kb] = r * 128 + ((kb * 64 + (g << 4)) ^ ((r & 7) << 4));
    }
  int pWOff[2][4];
  #pragma unroll
  for (int m = 0; m < 2; m++) {
    int r = m * 16 + lq;
    int swz = (r & 7) << 4;
    #pragma unroll
    for (int n = 0; n < 4; n++)
      pWOff[m][n] = r * 128 + ((n * 32 + g * 8) ^ swz);
  }

  int rowL[2], colL[2];
  #pragma unroll
  for (int i = 0; i < 2; i++) {
    int L = t * 16 + i * 4096;
    int r = L >> 7;
    rowL[i] = r;
    colL[i] = (L & 127) ^ ((r & 7) << 4);
  }
  const char* Kb = (const char*)Kc;
  const char* Vtb = (const char*)Vt;

  // stage K/V tile kt into buffer c (Kc rows stride 2048B, head off h*128B)
  auto stage = [&](int kt, int c) {
    const int kv0 = kt * 64;
    char* Kd = lds + c * 16384;
    char* Vd = Kd + 8192;
    #pragma unroll
    for (int i = 0; i < 2; i++) {
      gload_lds16(Kb + (size_t)(b * SEQ + kv0 + rowL[i]) * 2048 + h * 128 + colL[i],
                  Kd + i * 4096 + t * 16);
      gload_lds16(Vtb + (size_t)((b * NHEADS + h) * HD + rowL[i]) * (SEQ * 2) + kv0 * 2 + colL[i],
                  Vd + i * 4096 + t * 16);
    }
  };

  stage(0, 0);
  __syncthreads();
  int cur = 0;

  const int NT = SEQ / 64;
  for (int kt = 0; kt < NT; kt++) {
    if (kt + 1 < NT) stage(kt + 1, cur ^ 1);
    char* Klds = lds + cur * 16384;
    char* Vlds = Klds + 8192;
    const int kv0 = kt * 64;

    f32x4 sacc[2][4] = {};
    __builtin_amdgcn_s_setprio(1);
    #pragma unroll
    for (int kb = 0; kb < 2; kb++) {
      bf16x8 kf[4];
      #pragma unroll
      for (int n = 0; n < 4; n++)
        kf[n] = *(const bf16x8*)(Klds + kvOff[kb][n]);
      #pragma unroll
      for (int m = 0; m < 2; m++)
        #pragma unroll
        for (int n = 0; n < 4; n++)
          sacc[m][n] = __builtin_amdgcn_mfma_f32_16x16x32_bf16(kf[n], qf[m][kb], sacc[m][n], 0, 0, 0);
    }
    __builtin_amdgcn_s_setprio(0);

    if (use_mask) {
      #pragma unroll
      for (int m = 0; m < 2; m++) {
        int qg = q0 + m * 16 + lq;
        const float* mrow = mask + ((size_t)b * SEQ + qg) * SEQ + kv0;
        #pragma unroll
        for (int n = 0; n < 4; n++)
          #pragma unroll
          for (int j = 0; j < 4; j++)
            sacc[m][n][j] += mrow[n * 16 + g * 4 + j] * 1.44269504f;
      }
    }

    // tile max over BOTH m-tiles (shared, row-consistent after g-reduce)
    float pm;
    {
      f32x4 v4;
      #pragma unroll
      for (int j = 0; j < 4; j++)
        v4[j] = fmaxf(fmaxf(fmaxf(sacc[0][0][j], sacc[0][1][j]), fmaxf(sacc[0][2][j], sacc[0][3][j])),
                      fmaxf(fmaxf(sacc[1][0][j], sacc[1][1][j]), fmaxf(sacc[1][2][j], sacc[1][3][j])));
      pm = fmaxf(fmaxf(v4[0], v4[1]), fmaxf(v4[2], v4[3]));
      pm = fmaxf(pm, __shfl_xor(pm, 16, 64));
      pm = fmaxf(pm, __shfl_xor(pm, 32, 64));
    }

    // defer-max THR=8 (exp2 domain): single gate/rescale for both m-tiles
    if (!__all(pm <= mrun + 8.f)) {
      float mn = fmaxf(mrun, pm);
      float sf = exp2_fast(mrun - mn);
      mrun = mn;
      lrun[0] *= sf;
      lrun[1] *= sf;
      float sfj[4];
      #pragma unroll
      for (int j = 0; j < 4; j++) sfj[j] = __shfl(sf, (g << 2) + j, 64);
      #pragma unroll
      for (int m = 0; m < 2; m++)
        #pragma unroll
        for (int n = 0; n < 4; n++)
          #pragma unroll
          for (int j = 0; j < 4; j++)
            oacc[m][n][j] *= sfj[j];
    }

    #pragma unroll
    for (int m = 0; m < 2; m++) {
      float rsn[4];
      #pragma unroll
      for (int n = 0; n < 4; n++) {
        float e0 = exp2_fast(sacc[m][n][0] - mrun);
        float e1 = exp2_fast(sacc[m][n][1] - mrun);
        float e2 = exp2_fast(sacc[m][n][2] - mrun);
        float e3 = exp2_fast(sacc[m][n][3] - mrun);
        rsn[n] = (e0 + e1) + (e2 + e3);
        bf16x4 p = {(bf16)e0, (bf16)e1, (bf16)e2, (bf16)e3};
        *(bf16x4*)(Pw + pWOff[m][n]) = p;
      }
      lrun[m] += (rsn[0] + rsn[1]) + (rsn[2] + rsn[3]);
    }

    // (no explicit fence: compiler orders the P write->read on Pw itself)

    __builtin_amdgcn_s_setprio(1);
    #pragma unroll
    for (int kb = 0; kb < 2; kb++) {
      bf16x8 pf[2], vf[4];
      #pragma unroll
      for (int m = 0; m < 2; m++)
        pf[m] = *(const bf16x8*)(Pw + pROff[m][kb]);
      #pragma unroll
      for (int n = 0; n < 4; n++)
        vf[n] = *(const bf16x8*)(Vlds + kvOff[kb][n]);
      #pragma unroll
      for (int m = 0; m < 2; m++)
        #pragma unroll
        for (int n = 0; n < 4; n++)
          oacc[m][n] = __builtin_amdgcn_mfma_f32_16x16x32_bf16(pf[m], vf[n], oacc[m][n], 0, 0, 0);
    }
    __builtin_amdgcn_s_setprio(0);

    __syncthreads();
    cur ^= 1;
  }

  #pragma unroll
  for (int m = 0; m < 2; m++) {
    lrun[m] += __shfl_xor(lrun[m], 16, 64);
    lrun[m] += __shfl_xor(lrun[m], 32, 64);
  }

  #pragma unroll
  for (int m = 0; m < 2; m++) {
    float inv[4];
    #pragma unroll
    for (int j = 0; j < 4; j++)
      inv[j] = 1.f / __shfl(lrun[m], (g << 2) + j, 64);
    #pragma unroll
    for (int n = 0; n < 4; n++) {
      int cg = h * HD + n * 16 + lq;
      #pragma unroll
      for (int j = 0; j < 4; j++) {
        int rg = b * SEQ + q0 + m * 16 + g * 4 + j;
        vals[(size_t)rg * D_MODEL + cg] = (bf16)(oacc[m][n][j] * inv[j]);
      }
    }
  }
}

extern "C" void kernel_launch(void* const* d_in, const int* in_sizes, int n_in,
                              void* d_out, int out_size, void* d_ws, size_t ws_size,
                              hipStream_t stream) {
  const float* x    = (const float*)d_in[0];
  const float* y    = (const float*)d_in[1];
  const float* mask = (const float*)d_in[2];
  const float* Wkv  = (const float*)d_in[3];
  const float* bkv  = (const float*)d_in[4];
  const float* Wq   = (const float*)d_in[5];
  const float* bq   = (const float*)d_in[6];
  const float* Wo   = (const float*)d_in[7];
  const float* bo   = (const float*)d_in[8];
  float* out = (float*)d_out;

  char* ws = (char*)d_ws;
  bf16* Wkvt = (bf16*)(ws + (16ull << 20));      // 4 MB
  bf16* Wqt  = (bf16*)(ws + (20ull << 20));      // 2 MB
  bf16* Wot  = (bf16*)(ws + (22ull << 20));      // 2 MB
  bf16* Kc   = (bf16*)(ws + (24ull << 20));      // 8 MB  K compact [4096][1024]
  bf16* Qbuf = (bf16*)(ws + (40ull << 20));      // 8 MB
  bf16* Vt   = (bf16*)(ws + (48ull << 20));      // 8 MB
  bf16* vals = (bf16*)(ws + (56ull << 20));      // 8 MB
  int*  flag = (int*)(ws + (64ull << 20));       // 4 B

  const float QSCL = 0.125f * 1.44269504f;   // 1/sqrt(64) * log2(e)

  hipMemsetAsync(flag, 0, 4, stream);
  prep_kernel<<<1024, 256, 0, stream>>>(Wkv, Wq, Wo, Wkvt, Wqt, Wot);
  qkv_gemm<<<dim3(32, 32), 256, 0, stream>>>(x, y, Wkvt, Wqt, bkv, bq,
                                             mask, flag, Kc, Qbuf, Vt, QSCL);
  attn_kernel<<<512, 256, 0, stream>>>(Qbuf, Kc, Vt, mask, flag, vals);
  gemm_o<<<dim3(64, 8), 256, 0, stream>>>(vals, Wot, bo, out, 4096, 1024, 1024);
}

// Round 22
// 136.450 us; speedup vs baseline: 1.0460x; 1.0460x over previous
//
#include <hip/hip_runtime.h>
#include <hip/hip_bf16.h>

#define D_MODEL 1024
#define NHEADS 16
#define HD 64
#define BATCH 2
#define SEQ 2048
#define BS (BATCH*SEQ)   // 4096

typedef __bf16 bf16;
typedef bf16 bf16x4 __attribute__((ext_vector_type(4)));
typedef bf16 bf16x8 __attribute__((ext_vector_type(8)));
typedef float f32x4 __attribute__((ext_vector_type(4)));

#define AS1 __attribute__((address_space(1)))
#define AS3 __attribute__((address_space(3)))

__device__ __forceinline__ void gload_lds16(const void* g, void* l) {
  __builtin_amdgcn_global_load_lds((AS1 const unsigned int*)g, (AS3 unsigned int*)l, 16, 0, 0);
}

// 2^x: prefer the compiler builtin (raw v_exp_f32); asm fallback.
__device__ __forceinline__ float exp2_fast(float x) {
#if __has_builtin(__builtin_amdgcn_exp2f)
  return __builtin_amdgcn_exp2f(x);
#else
  float r;
  asm("v_exp_f32 %0, %1\n\ts_nop 1" : "=v"(r) : "v"(x));
  return r;
#endif
}

// ---------------- fused prep: cvt x, cvt y, 3 weight transposes --------------
// (bf16 conversion of x/y is a bandwidth compressor: A is re-read once per
// column-tile in qkv, so converting once up front halves those passes' bytes
// AND keeps A-staging on the async gload_lds path. r21 measured the direct-f32
// alternative at +36 µs. Mask scan lives in the qkv dispatch.)
__global__ __launch_bounds__(256)
void prep_kernel(const float* __restrict__ x, const float* __restrict__ y,
                 const float* __restrict__ Wkv, const float* __restrict__ Wq,
                 const float* __restrict__ Wo,
                 bf16* __restrict__ xb, bf16* __restrict__ yb,
                 bf16* __restrict__ Wkvt, bf16* __restrict__ Wqt,
                 bf16* __restrict__ Wot) {
  __shared__ bf16 tile[64][72];
  const int blk = blockIdx.x;
  const int t = threadIdx.x;

  if (blk < 4096) {
    const float* in = (blk < 2048) ? x : y;
    bf16* out = (blk < 2048) ? xb : yb;
    int i = (blk & 2047) * 256 + t;
    const float4* p = (const float4*)(in + (size_t)i * 8);
    float4 a = p[0], b = p[1];
    bf16x8 o;
    o[0]=(bf16)a.x; o[1]=(bf16)a.y; o[2]=(bf16)a.z; o[3]=(bf16)a.w;
    o[4]=(bf16)b.x; o[5]=(bf16)b.y; o[6]=(bf16)b.z; o[7]=(bf16)b.w;
    *(bf16x8*)(out + (size_t)i * 8) = o;
  } else {
    const float* tin; bf16* tout; int C, tt;
    if (blk < 4608)      { tin = Wkv; tout = Wkvt; C = 2048; tt = blk - 4096; }
    else if (blk < 4864) { tin = Wq;  tout = Wqt;  C = 1024; tt = blk - 4608; }
    else                 { tin = Wo;  tout = Wot;  C = 1024; tt = blk - 4864; }
    const int R = 1024;
    const int r0 = (tt & 15) * 64;
    const int c0 = (tt >> 4) * 64;
    {
      int r = t >> 2, cc = (t & 3) * 16;
      const float* src = tin + (size_t)(r0 + r) * C + c0 + cc;
      #pragma unroll
      for (int j = 0; j < 16; j += 4) {
        float4 v = *(const float4*)(src + j);
        tile[r][cc + j + 0] = (bf16)v.x;
        tile[r][cc + j + 1] = (bf16)v.y;
        tile[r][cc + j + 2] = (bf16)v.z;
        tile[r][cc + j + 3] = (bf16)v.w;
      }
    }
    __syncthreads();
    {
      int c = t >> 2, rr = (t & 3) * 16;
      bf16* dst = tout + (size_t)(c0 + c) * R + r0 + rr;
      bf16x8 o0, o1;
      #pragma unroll
      for (int j = 0; j < 8; j++) { o0[j] = tile[rr + j][c]; o1[j] = tile[rr + 8 + j][c]; }
      *(bf16x8*)dst = o0;
      *(bf16x8*)(dst + 8) = o1;
    }
  }
}

// ---------------- fused QKV projection GEMM + mask scan ----------------------
// grid (32, 32):
//   by<16        -> KV tile: wc==0 waves write K half COMPACTED to
//                   Kc[4096][1024] (col = h*64+d); wc==1 waves write V half
//                   TRANSPOSED to Vt.
//   by in [16,24)-> Q tile (scaled by QSCL into exp2 domain).
//   by in [24,32)-> mask zero-scan blocks (memory-bound; overlap with the
//                   compute-bound GEMM blocks hides the 33.5MB read).
__global__ __launch_bounds__(256)
void qkv_gemm(const bf16* __restrict__ xb, const bf16* __restrict__ yb,
              const bf16* __restrict__ Wkvt, const bf16* __restrict__ Wqt,
              const float* __restrict__ bkv, const float* __restrict__ bq,
              const float* __restrict__ mask, int* __restrict__ flag,
              bf16* __restrict__ Kc, bf16* __restrict__ Qbuf,
              bf16* __restrict__ Vt, float QSCL) {
  const int by = blockIdx.y;
  const int t = threadIdx.x;

  if (by >= 24) {
    // mask zero-scan: 256 blocks x 256 threads, grid-stride over float4s
    const int n4 = BATCH * SEQ * SEQ / 4;
    int i = ((by - 24) * 32 + blockIdx.x) * 256 + t;
    const int stride = 256 * 256;
    int any = 0;
    for (; i < n4; i += stride) {
      float4 v = *(const float4*)(mask + (size_t)i * 4);
      if (v.x != 0.f || v.y != 0.f || v.z != 0.f || v.w != 0.f) any = 1;
    }
    if (__ballot(any) && (t & 63) == 0) atomicOr(flag, 1);
    return;
  }

  __shared__ char lds[32768];
  char* Alds = lds;
  char* Blds = lds + 16384;
  const int K = 1024;
  const int lane = t & 63;
  const int wid = t >> 6;
  const int m0 = blockIdx.x * 128;
  const bool isQ = by >= 16;
  const int n0 = (isQ ? by - 16 : by) * 128;
  const bf16* A = isQ ? yb : xb;
  const bf16* Bt = isQ ? Wqt : Wkvt;
  const int wr = wid >> 1, wc = wid & 1;

  f32x4 acc[4][4] = {};

  int rowL[4], colL[4];
  #pragma unroll
  for (int i = 0; i < 4; i++) {
    int L = t * 16 + i * 4096;
    int r = L >> 7;
    rowL[i] = r;
    colL[i] = (L & 127) ^ ((r & 7) << 4);
  }
  const char* Ab = (const char*)A;
  const char* Bb = (const char*)Bt;
  const size_t rs = (size_t)K * 2;

  for (int k0 = 0; k0 < K; k0 += 64) {
    #pragma unroll
    for (int i = 0; i < 4; i++) {
      gload_lds16(Ab + (size_t)(m0 + rowL[i]) * rs + (size_t)k0 * 2 + colL[i],
                  Alds + i * 4096 + t * 16);
      gload_lds16(Bb + (size_t)(n0 + rowL[i]) * rs + (size_t)k0 * 2 + colL[i],
                  Blds + i * 4096 + t * 16);
    }
    __syncthreads();
    #pragma unroll
    for (int kb = 0; kb < 2; kb++) {
      bf16x8 af[4], bfr[4];
      #pragma unroll
      for (int m = 0; m < 4; m++) {
        int r = wr * 64 + m * 16 + (lane & 15);
        int cb = (kb * 64 + ((lane >> 4) << 4)) ^ ((r & 7) << 4);
        af[m] = *(const bf16x8*)(Alds + r * 128 + cb);
      }
      #pragma unroll
      for (int n = 0; n < 4; n++) {
        int r = wc * 64 + n * 16 + (lane & 15);
        int cb = (kb * 64 + ((lane >> 4) << 4)) ^ ((r & 7) << 4);
        bfr[n] = *(const bf16x8*)(Blds + r * 128 + cb);
      }
      #pragma unroll
      for (int m = 0; m < 4; m++)
        #pragma unroll
        for (int n = 0; n < 4; n++)
          acc[m][n] = __builtin_amdgcn_mfma_f32_16x16x32_bf16(af[m], bfr[n], acc[m][n], 0, 0, 0);
    }
    __syncthreads();
  }

  if (!isQ && wc == 1) {
    // V half -> Vt[B][H][HD][SEQ], transposed in epilogue
    const int h = n0 >> 7;
    const int bb = m0 >> 11;
    #pragma unroll
    for (int n = 0; n < 4; n++) {
      const int d = n * 16 + (lane & 15);
      const float bv = bkv[n0 + 64 + d];
      bf16* vrow = Vt + ((size_t)((bb * NHEADS + h) * HD + d)) * SEQ;
      #pragma unroll
      for (int m = 0; m < 4; m++) {
        const int rb = m0 + wr * 64 + m * 16 + ((lane >> 4) << 2);
        const int s = rb & (SEQ - 1);
        bf16x4 v;
        #pragma unroll
        for (int j = 0; j < 4; j++) v[j] = (bf16)(acc[m][n][j] + bv);
        *(bf16x4*)(vrow + s) = v;
      }
    }
  } else if (!isQ) {
    // K half -> Kc[4096][1024], col = h*64 + d  (h = n0>>7, d = n*16+lq)
    #pragma unroll
    for (int m = 0; m < 4; m++) {
      const int rb = m0 + wr * 64 + m * 16 + ((lane >> 4) << 2);
      #pragma unroll
      for (int n = 0; n < 4; n++) {
        const int cg = n0 + n * 16 + (lane & 15);            // bias index
        const int cc = (n0 >> 1) + n * 16 + (lane & 15);     // compact col
        const float bv = bkv[cg];
        #pragma unroll
        for (int j = 0; j < 4; j++)
          Kc[(size_t)(rb + j) * 1024 + cc] = (bf16)(acc[m][n][j] + bv);
      }
    }
  } else {
    #pragma unroll
    for (int m = 0; m < 4; m++) {
      const int rb = m0 + wr * 64 + m * 16 + ((lane >> 4) << 2);
      #pragma unroll
      for (int n = 0; n < 4; n++) {
        const int cg = n0 + wc * 64 + n * 16 + (lane & 15);
        const float bv = bq[cg];
        #pragma unroll
        for (int j = 0; j < 4; j++)
          Qbuf[(size_t)(rb + j) * 1024 + cg] = (bf16)((acc[m][n][j] + bv) * QSCL);
      }
    }
  }
}

// ---------------- O GEMM: out = vals @ Wot^T + bo, 64x128 tiles --------------
__global__ __launch_bounds__(256)
void gemm_o(const bf16* __restrict__ A, const bf16* __restrict__ Bt,
            const float* __restrict__ bias, float* __restrict__ C,
            int M, int N, int K) {
  __shared__ char lds[24576];
  char* Alds = lds;            // 64 rows x 128B
  char* Blds = lds + 8192;     // 128 rows x 128B
  const int t = threadIdx.x;
  const int lane = t & 63;
  const int wid = t >> 6;
  const int m0 = blockIdx.x * 64;
  const int n0 = blockIdx.y * 128;
  const int wr = wid >> 1, wc = wid & 1;

  f32x4 acc[2][4] = {};

  int rowL[4], colL[4];
  #pragma unroll
  for (int i = 0; i < 4; i++) {
    int L = t * 16 + i * 4096;
    int r = L >> 7;
    rowL[i] = r;
    colL[i] = (L & 127) ^ ((r & 7) << 4);
  }
  const char* Ab = (const char*)A;
  const char* Bb = (const char*)Bt;
  const size_t rs = (size_t)K * 2;

  for (int k0 = 0; k0 < K; k0 += 64) {
    #pragma unroll
    for (int i = 0; i < 2; i++)
      gload_lds16(Ab + (size_t)(m0 + rowL[i]) * rs + (size_t)k0 * 2 + colL[i],
                  Alds + i * 4096 + t * 16);
    #pragma unroll
    for (int i = 0; i < 4; i++)
      gload_lds16(Bb + (size_t)(n0 + rowL[i]) * rs + (size_t)k0 * 2 + colL[i],
                  Blds + i * 4096 + t * 16);
    __syncthreads();
    #pragma unroll
    for (int kb = 0; kb < 2; kb++) {
      bf16x8 af[2], bfr[4];
      #pragma unroll
      for (int m = 0; m < 2; m++) {
        int r = wr * 32 + m * 16 + (lane & 15);
        int cb = (kb * 64 + ((lane >> 4) << 4)) ^ ((r & 7) << 4);
        af[m] = *(const bf16x8*)(Alds + r * 128 + cb);
      }
      #pragma unroll
      for (int n = 0; n < 4; n++) {
        int r = wc * 64 + n * 16 + (lane & 15);
        int cb = (kb * 64 + ((lane >> 4) << 4)) ^ ((r & 7) << 4);
        bfr[n] = *(const bf16x8*)(Blds + r * 128 + cb);
      }
      #pragma unroll
      for (int m = 0; m < 2; m++)
        #pragma unroll
        for (int n = 0; n < 4; n++)
          acc[m][n] = __builtin_amdgcn_mfma_f32_16x16x32_bf16(af[m], bfr[n], acc[m][n], 0, 0, 0);
    }
    __syncthreads();
  }

  #pragma unroll
  for (int m = 0; m < 2; m++) {
    const int rb = m0 + wr * 32 + m * 16 + ((lane >> 4) << 2);
    #pragma unroll
    for (int n = 0; n < 4; n++) {
      const int cg = n0 + wc * 64 + n * 16 + (lane & 15);
      const float bv = bias[cg];
      #pragma unroll
      for (int j = 0; j < 4; j++)
        C[(size_t)(rb + j) * N + cg] = acc[m][n][j] + bv;
    }
  }
}

// ---------------- flash attention (r19 structure, verbatim) ------------------
// 4 waves x 32 q-rows = 128 q/block; grid = 512; 2 blocks/CU (measured
// optimum). Swapped QK^T; shared mrun across m (row-consistent); defer-max
// THR=8; per-lane lrun; builtin exp2; no fences.
__global__ __launch_bounds__(256)
void attn_kernel(const bf16* __restrict__ Qb, const bf16* __restrict__ Kc,
                 const bf16* __restrict__ Vt, const float* __restrict__ mask,
                 const int* __restrict__ flag, bf16* __restrict__ vals) {
  __shared__ char lds[49152];
  const int t = threadIdx.x;
  const int lane = t & 63;
  const int wid = t >> 6;
  const int g = lane >> 4;
  const int lq = lane & 15;
  char* Pw = lds + 32768 + wid * 4096;

  // XCD swizzle: 512 blocks, 8 XCDs, 64 consecutive wgs/XCD (4 heads).
  int wg = ((blockIdx.x & 7) << 6) | (blockIdx.x >> 3);
  const int qt = wg & 15;
  const int h = (wg >> 4) & 15;
  const int b = wg >> 8;
  const int q0 = qt * 128 + wid * 32;
  const bool use_mask = (*flag) != 0;

  bf16x8 qf[2][2];
  #pragma unroll
  for (int m = 0; m < 2; m++)
    #pragma unroll
    for (int kb = 0; kb < 2; kb++) {
      int r = q0 + m * 16 + lq;
      qf[m][kb] = *(const bf16x8*)(Qb + (size_t)(b * SEQ + r) * D_MODEL + h * HD + kb * 32 + g * 8);
    }

  f32x4 oacc[2][4] = {};
  float mrun = -1e30f;
  float lrun[2] = {0.f, 0.f};

  int kvOff[2][4];
  #pragma unroll
  for (int kb = 0; kb < 2; kb++)
    #pragma unroll
    for (int n = 0; n < 4; n++) {
      int r = n * 16 + lq;
      kvOff[kb][n] = r * 128 + ((kb * 64 + (g << 4)) ^ ((r & 7) << 4));
    }
  int pROff[2][2];
  #pragma unroll
  for (int m = 0; m < 2; m++)
    #pragma unroll
    for (int kb = 0; kb < 2; kb++) {
      int r = m * 16 + lq;
      pROff[m][kb] = r * 128 + ((kb * 64 + (g << 4)) ^ ((r & 7) << 4));
    }
  int pWOff[2][4];
  #pragma unroll
  for (int m = 0; m < 2; m++) {
    int r = m * 16 + lq;
    int swz = (r & 7) << 4;
    #pragma unroll
    for (int n = 0; n < 4; n++)
      pWOff[m][n] = r * 128 + ((n * 32 + g * 8) ^ swz);
  }

  int rowL[2], colL[2];
  #pragma unroll
  for (int i = 0; i < 2; i++) {
    int L = t * 16 + i * 4096;
    int r = L >> 7;
    rowL[i] = r;
    colL[i] = (L & 127) ^ ((r & 7) << 4);
  }
  const char* Kb = (const char*)Kc;
  const char* Vtb = (const char*)Vt;

  // stage K/V tile kt into buffer c (Kc rows stride 2048B, head off h*128B)
  auto stage = [&](int kt, int c) {
    const int kv0 = kt * 64;
    char* Kd = lds + c * 16384;
    char* Vd = Kd + 8192;
    #pragma unroll
    for (int i = 0; i < 2; i++) {
      gload_lds16(Kb + (size_t)(b * SEQ + kv0 + rowL[i]) * 2048 + h * 128 + colL[i],
                  Kd + i * 4096 + t * 16);
      gload_lds16(Vtb + (size_t)((b * NHEADS + h) * HD + rowL[i]) * (SEQ * 2) + kv0 * 2 + colL[i],
                  Vd + i * 4096 + t * 16);
    }
  };

  stage(0, 0);
  __syncthreads();
  int cur = 0;

  const int NT = SEQ / 64;
  for (int kt = 0; kt < NT; kt++) {
    if (kt + 1 < NT) stage(kt + 1, cur ^ 1);
    char* Klds = lds + cur * 16384;
    char* Vlds = Klds + 8192;
    const int kv0 = kt * 64;

    f32x4 sacc[2][4] = {};
    __builtin_amdgcn_s_setprio(1);
    #pragma unroll
    for (int kb = 0; kb < 2; kb++) {
      bf16x8 kf[4];
      #pragma unroll
      for (int n = 0; n < 4; n++)
        kf[n] = *(const bf16x8*)(Klds + kvOff[kb][n]);
      #pragma unroll
      for (int m = 0; m < 2; m++)
        #pragma unroll
        for (int n = 0; n < 4; n++)
          sacc[m][n] = __builtin_amdgcn_mfma_f32_16x16x32_bf16(kf[n], qf[m][kb], sacc[m][n], 0, 0, 0);
    }
    __builtin_amdgcn_s_setprio(0);

    if (use_mask) {
      #pragma unroll
      for (int m = 0; m < 2; m++) {
        int qg = q0 + m * 16 + lq;
        const float* mrow = mask + ((size_t)b * SEQ + qg) * SEQ + kv0;
        #pragma unroll
        for (int n = 0; n < 4; n++)
          #pragma unroll
          for (int j = 0; j < 4; j++)
            sacc[m][n][j] += mrow[n * 16 + g * 4 + j] * 1.44269504f;
      }
    }

    // tile max over BOTH m-tiles (shared, row-consistent after g-reduce)
    float pm;
    {
      f32x4 v4;
      #pragma unroll
      for (int j = 0; j < 4; j++)
        v4[j] = fmaxf(fmaxf(fmaxf(sacc[0][0][j], sacc[0][1][j]), fmaxf(sacc[0][2][j], sacc[0][3][j])),
                      fmaxf(fmaxf(sacc[1][0][j], sacc[1][1][j]), fmaxf(sacc[1][2][j], sacc[1][3][j])));
      pm = fmaxf(fmaxf(v4[0], v4[1]), fmaxf(v4[2], v4[3]));
      pm = fmaxf(pm, __shfl_xor(pm, 16, 64));
      pm = fmaxf(pm, __shfl_xor(pm, 32, 64));
    }

    // defer-max THR=8 (exp2 domain): single gate/rescale for both m-tiles
    if (!__all(pm <= mrun + 8.f)) {
      float mn = fmaxf(mrun, pm);
      float sf = exp2_fast(mrun - mn);
      mrun = mn;
      lrun[0] *= sf;
      lrun[1] *= sf;
      float sfj[4];
      #pragma unroll
      for (int j = 0; j < 4; j++) sfj[j] = __shfl(sf, (g << 2) + j, 64);
      #pragma unroll
      for (int m = 0; m < 2; m++)
        #pragma unroll
        for (int n = 0; n < 4; n++)
          #pragma unroll
          for (int j = 0; j < 4; j++)
            oacc[m][n][j] *= sfj[j];
    }

    #pragma unroll
    for (int m = 0; m < 2; m++) {
      float rsn[4];
      #pragma unroll
      for (int n = 0; n < 4; n++) {
        float e0 = exp2_fast(sacc[m][n][0] - mrun);
        float e1 = exp2_fast(sacc[m][n][1] - mrun);
        float e2 = exp2_fast(sacc[m][n][2] - mrun);
        float e3 = exp2_fast(sacc[m][n][3] - mrun);
        rsn[n] = (e0 + e1) + (e2 + e3);
        bf16x4 p = {(bf16)e0, (bf16)e1, (bf16)e2, (bf16)e3};
        *(bf16x4*)(Pw + pWOff[m][n]) = p;
      }
      lrun[m] += (rsn[0] + rsn[1]) + (rsn[2] + rsn[3]);
    }

    // (no explicit fence: compiler orders the P write->read on Pw itself)

    __builtin_amdgcn_s_setprio(1);
    #pragma unroll
    for (int kb = 0; kb < 2; kb++) {
      bf16x8 pf[2], vf[4];
      #pragma unroll
      for (int m = 0; m < 2; m++)
        pf[m] = *(const bf16x8*)(Pw + pROff[m][kb]);
      #pragma unroll
      for (int n = 0; n < 4; n++)
        vf[n] = *(const bf16x8*)(Vlds + kvOff[kb][n]);
      #pragma unroll
      for (int m = 0; m < 2; m++)
        #pragma unroll
        for (int n = 0; n < 4; n++)
          oacc[m][n] = __builtin_amdgcn_mfma_f32_16x16x32_bf16(pf[m], vf[n], oacc[m][n], 0, 0, 0);
    }
    __builtin_amdgcn_s_setprio(0);

    __syncthreads();
    cur ^= 1;
  }

  #pragma unroll
  for (int m = 0; m < 2; m++) {
    lrun[m] += __shfl_xor(lrun[m], 16, 64);
    lrun[m] += __shfl_xor(lrun[m], 32, 64);
  }

  #pragma unroll
  for (int m = 0; m < 2; m++) {
    float inv[4];
    #pragma unroll
    for (int j = 0; j < 4; j++)
      inv[j] = 1.f / __shfl(lrun[m], (g << 2) + j, 64);
    #pragma unroll
    for (int n = 0; n < 4; n++) {
      int cg = h * HD + n * 16 + lq;
      #pragma unroll
      for (int j = 0; j < 4; j++) {
        int rg = b * SEQ + q0 + m * 16 + g * 4 + j;
        vals[(size_t)rg * D_MODEL + cg] = (bf16)(oacc[m][n][j] * inv[j]);
      }
    }
  }
}

extern "C" void kernel_launch(void* const* d_in, const int* in_sizes, int n_in,
                              void* d_out, int out_size, void* d_ws, size_t ws_size,
                              hipStream_t stream) {
  const float* x    = (const float*)d_in[0];
  const float* y    = (const float*)d_in[1];
  const float* mask = (const float*)d_in[2];
  const float* Wkv  = (const float*)d_in[3];
  const float* bkv  = (const float*)d_in[4];
  const float* Wq   = (const float*)d_in[5];
  const float* bq   = (const float*)d_in[6];
  const float* Wo   = (const float*)d_in[7];
  const float* bo   = (const float*)d_in[8];
  float* out = (float*)d_out;

  char* ws = (char*)d_ws;
  bf16* xb   = (bf16*)(ws);                      // 8 MB
  bf16* yb   = (bf16*)(ws + (8ull << 20));       // 8 MB
  bf16* Wkvt = (bf16*)(ws + (16ull << 20));      // 4 MB
  bf16* Wqt  = (bf16*)(ws + (20ull << 20));      // 2 MB
  bf16* Wot  = (bf16*)(ws + (22ull << 20));      // 2 MB
  bf16* Kc   = (bf16*)(ws + (24ull << 20));      // 8 MB  K compact [4096][1024]
  bf16* Qbuf = (bf16*)(ws + (40ull << 20));      // 8 MB
  bf16* Vt   = (bf16*)(ws + (48ull << 20));      // 8 MB
  bf16* vals = (bf16*)(ws + (56ull << 20));      // 8 MB
  int*  flag = (int*)(ws + (64ull << 20));       // 4 B

  const float QSCL = 0.125f * 1.44269504f;   // 1/sqrt(64) * log2(e)

  hipMemsetAsync(flag, 0, 4, stream);
  prep_kernel<<<5120, 256, 0, stream>>>(x, y, Wkv, Wq, Wo,
                                        xb, yb, Wkvt, Wqt, Wot);
  qkv_gemm<<<dim3(32, 32), 256, 0, stream>>>(xb, yb, Wkvt, Wqt, bkv, bq,
                                             mask, flag, Kc, Qbuf, Vt, QSCL);
  attn_kernel<<<512, 256, 0, stream>>>(Qbuf, Kc, Vt, mask, flag, vals);
  gemm_o<<<dim3(64, 8), 256, 0, stream>>>(vals, Wot, bo, out, 4096, 1024, 1024);
}